// Round 23
// baseline (3044.080 us; speedup 1.0000x reference)
//
#include <hip/hip_runtime.h>

#define TMAX 8192
#define H 128

typedef int   i32x4 __attribute__((ext_vector_type(4)));

__device__ __forceinline__ float sigf(float x) {
    return __builtin_amdgcn_rcpf(1.f + __expf(-x));
}
__device__ __forceinline__ float tanhf_fast(float x) {
    return fmaf(2.f, __builtin_amdgcn_rcpf(1.f + __expf(-2.f * x)), -1.f);
}

// One block, 512 threads = 8 waves (2/SIMD).
//
// ROUND 23 = R15 VERBATIM — the fastest kernel with a trustworthy full-harness
// pass (3033 us, absmax 9.77e-4 pre AND post timing).
// R22 proved the R19 asm-MFMA variant is NONDETERMINISTIC (same binary:
// pre-check 1.95e-3, post-timing 3.91e-3) — a timing-dependent hazard in
// compiler waitcnt placement around register-only inline asm (rule #18
// class). Builtin MFMA keeps the dataflow visible to the compiler ->
// guaranteed waits -> deterministic.
// Structure: int8 MFMA matvec (mfma_i32_16x16x64_i8, 2x bf16 rate), per-row
// W quantization (127/rowmax), int8 h feedback via LDS (scale 127), fp32
// 4-way-redundant epilogue, one barrier/step, double-buffered h.
__attribute__((amdgpu_waves_per_eu(2, 2)))
__global__ __launch_bounds__(512)
void lstm_seq_kernel(const float* __restrict__ x,
                     const float* __restrict__ Wih,
                     const float* __restrict__ Whh,
                     const float* __restrict__ bih,
                     const float* __restrict__ bhh,
                     const float* __restrict__ Wlin,
                     const float* __restrict__ blin,
                     const float* __restrict__ h0,
                     const float* __restrict__ c0,
                     float* __restrict__ out,
                     int T)
{
    __shared__ float  x_s[TMAX];    // 32 KB
    __shared__ float  srow[512];    // per-row |W|max (2 KB)
    __shared__ i32x4  hv4[2][8];    // double-buffered h as 128 int8

    const int t   = threadIdx.x;    // 0..511
    const int l   = t & 63;
    const int w   = t >> 6;         // wave 0..7
    const int m   = l & 15;         // A row-within-tile / C col
    const int g16 = l >> 4;         // C row-group

    for (int idx = t; idx < T; idx += 512) x_s[idx] = x[idx];

    // ---- per-row absmax of Whh (one row per thread, one-time) ----
    {
        const float* row = Whh + t * H;
        float mx = 0.f;
        for (int k = 0; k < H; ++k) mx = fmaxf(mx, fabsf(row[k]));
        srow[t] = fmaxf(mx, 1e-30f);
    }
    __syncthreads();

    // ---- pack A fragments: int8, per-row scale 127/rowmax ----
    // Tile tau: within-tile row m -> gate m&3, jj m>>2;
    // R = (m&3)*H + w*16 + tau*4 + (m>>2). Elem i of chunk c:
    // K = c*64 + g16*16 + i (k-map verified bit-exact in R12).
    i32x4 Aq[4][2];
    #pragma unroll
    for (int tau = 0; tau < 4; ++tau) {
        const int R = (m & 3) * H + w * 16 + tau * 4 + (m >> 2);
        const float inv = 127.f / srow[R];
        const float* rp = Whh + R * H;
        #pragma unroll
        for (int c = 0; c < 2; ++c) {
            int wd0 = 0, wd1 = 0, wd2 = 0, wd3 = 0;
            #pragma unroll
            for (int i = 0; i < 4; ++i) {
                const int base = c * 64 + g16 * 16;
                wd0 |= (((int)rintf(rp[base +  0 + i] * inv)) & 0xFF) << (i * 8);
                wd1 |= (((int)rintf(rp[base +  4 + i] * inv)) & 0xFF) << (i * 8);
                wd2 |= (((int)rintf(rp[base +  8 + i] * inv)) & 0xFF) << (i * 8);
                wd3 |= (((int)rintf(rp[base + 12 + i] * inv)) & 0xFF) << (i * 8);
            }
            Aq[tau][c] = (i32x4){wd0, wd1, wd2, wd3};
        }
    }

    // ---- epilogue constants (fp32 path) ----
    const int tsel  = (l >> 2) & 3;
    const int jproc = w * 16 + tsel * 4 + g16;
    // gate r of jproc came from A-row r*H + jproc; descale = rowmax/(127*127).
    const float sc0 = srow[0 * H + jproc] * (1.f / 16129.f);
    const float sc1 = srow[1 * H + jproc] * (1.f / 16129.f);
    const float sc2 = srow[2 * H + jproc] * (1.f / 16129.f);
    const float sc3 = srow[3 * H + jproc] * (1.f / 16129.f);
    const float wx0 = Wih[0 * H + jproc];
    const float wx1 = Wih[1 * H + jproc];
    const float wx2 = Wih[2 * H + jproc];
    const float wx3 = Wih[3 * H + jproc];
    const float b0  = bih[0 * H + jproc] + bhh[0 * H + jproc];
    const float b1  = bih[1 * H + jproc] + bhh[1 * H + jproc];
    const float b2  = bih[2 * H + jproc] + bhh[2 * H + jproc];
    const float b3  = bih[3 * H + jproc] + bhh[3 * H + jproc];
    float c = c0[jproc];                 // 4-way redundant (bit-identical math)
    const bool writer = ((l & 3) == 0);  // one col per (tile,jj) writes h

    const i32x4 zeroC = {0, 0, 0, 0};    // persistent zero C-in

    if (t < H) {
        ((signed char*)hv4[0])[t] = (signed char)(int)rintf(h0[t] * 127.f);
    }
    __syncthreads();

#define MFMA(A, B, C) __builtin_amdgcn_mfma_i32_16x16x64_i8((A), (B), (C), 0, 0, 0)
#define SEL(K) ((tsel & 2) ? ((tsel & 1) ? a3[K] : a2[K]) \
                           : ((tsel & 1) ? a1[K] : a0[K]))

#define STEP(RD, WR, SIDX) { \
    const float xv = x_s[SIDX]; \
    const i32x4 B0 = hv4[RD][g16]; \
    const i32x4 B1 = hv4[RD][4 + g16]; \
    i32x4 a0 = MFMA(Aq[0][0], B0, zeroC); \
    i32x4 a1 = MFMA(Aq[1][0], B0, zeroC); \
    i32x4 a2 = MFMA(Aq[2][0], B0, zeroC); \
    i32x4 a3 = MFMA(Aq[3][0], B0, zeroC); \
    a0 = MFMA(Aq[0][1], B1, a0); \
    a1 = MFMA(Aq[1][1], B1, a1); \
    a2 = MFMA(Aq[2][1], B1, a2); \
    a3 = MFMA(Aq[3][1], B1, a3); \
    const float gi = fmaf((float)SEL(0), sc0, fmaf(xv, wx0, b0)); \
    const float gf = fmaf((float)SEL(1), sc1, fmaf(xv, wx1, b1)); \
    const float gg = fmaf((float)SEL(2), sc2, fmaf(xv, wx2, b2)); \
    const float go = fmaf((float)SEL(3), sc3, fmaf(xv, wx3, b3)); \
    const float ig = sigf(gi); \
    const float fg = sigf(gf); \
    const float g2 = tanhf_fast(gg); \
    const float og = sigf(go); \
    c = fmaf(fg, c, ig * g2); \
    const float hn = og * tanhf_fast(c); \
    if (writer) ((signed char*)hv4[WR])[jproc] = (signed char)(int)rintf(hn * 127.f); \
    __syncthreads(); }

    const int Teven = T & ~1;
    for (int s = 0; s < Teven; s += 2) {
        STEP(0, 1, s)
        STEP(1, 0, s + 1)
    }
    if (T & 1) { STEP(0, 1, T - 1) }
    const signed char* hf = (const signed char*)hv4[T & 1];
#undef STEP
#undef SEL
#undef MFMA

    // Final linear: out = dot(W_lin, h_T) + b_lin (wave 0).
    if (t < 64) {
        const float h0f = (float)hf[t]      * (1.f / 127.f);
        const float h1f = (float)hf[t + 64] * (1.f / 127.f);
        float v = Wlin[t] * h0f + Wlin[t + 64] * h1f;
        #pragma unroll
        for (int off = 32; off >= 1; off >>= 1) v += __shfl_down(v, off);
        if (t == 0) out[0] = v + blin[0];
    }
}

extern "C" void kernel_launch(void* const* d_in, const int* in_sizes, int n_in,
                              void* d_out, int out_size, void* d_ws, size_t ws_size,
                              hipStream_t stream) {
    const float* x    = (const float*)d_in[0];
    const float* Wih  = (const float*)d_in[1];
    const float* Whh  = (const float*)d_in[2];
    const float* bih  = (const float*)d_in[3];
    const float* bhh  = (const float*)d_in[4];
    const float* Wlin = (const float*)d_in[5];
    const float* blin = (const float*)d_in[6];
    const float* h0   = (const float*)d_in[7];
    const float* c0   = (const float*)d_in[8];
    float* out = (float*)d_out;
    const int T = in_sizes[0];

    lstm_seq_kernel<<<1, 512, 0, stream>>>(x, Wih, Whh, bih, bhh, Wlin, blin,
                                           h0, c0, out, T);
}